// Round 13
// baseline (42.197 us; speedup 1.0000x reference)
//
#include <hip/hip_runtime.h>
#include <math.h>

#define BINS 10
#define BLOCK 256
#define WAVES (BLOCK / 64)
#define NR 8                       // pipeline rounds per tile
#define TILE (NR * BLOCK)          // float4s per tile = 2048
#define NBLK 2048

// async global->LDS DMA, 16B per lane, wave-uniform LDS base + lane*16
#define GLOAD16(gsrc, ldst)                                         \
    __builtin_amdgcn_global_load_lds(                               \
        (const __attribute__((address_space(1))) void*)(gsrc),      \
        (__attribute__((address_space(3))) void*)(ldst), 16, 0, 0)

// ---------------------------------------------------------------------------
// Pass 1. Lean math + single packed ds_add_u64/elem (count@bit40|bce*2^20).
// NEW vs R12: loads go through global_load_lds DMA (no VGPR round-trip ->
// nothing for the compiler to sink; R8-R12 all collapsed register prefetch
// to 2-outstanding, VGPR=20-24 proved it). Wave-private double-buffered
// stage slices: each wave stages AND consumes its own 1KB x + 1KB t slice,
// so the main loop needs NO __syncthreads (no conservative vmcnt(0) drain).
// Depth-2 pipeline held by literal counted waits: vmcnt(2) steady state.
// ---------------------------------------------------------------------------

__global__ __launch_bounds__(BLOCK) void ghm_pass1(
        const float4* __restrict__ x4, const float4* __restrict__ t4,
        const float* __restrict__ xs, const float* __restrict__ ts,
        float* __restrict__ psum, unsigned int* __restrict__ pcnt,
        int nvec, int total) {
    __shared__ unsigned long long hist[BINS * BLOCK];          // 20 KiB
    __shared__ __align__(16) unsigned char stg[2][WAVES][2048]; // 16 KiB
    const int tid  = threadIdx.x;
    const int wid  = tid >> 6;
    const int lane = tid & 63;
#pragma unroll
    for (int b = 0; b < BINS; ++b) hist[b * BLOCK + tid] = 0ull;
    __syncthreads();

    const float L2E    = 1.44269504088896f;   // log2(e)
    const float LN2    = 0.69314718055995f;   // ln(2)
    const float QSCALE = 1048576.0f;          // 2^20 fixed point
    unsigned long long* __restrict__ mycol = &hist[tid];

    auto proc = [&](float xv, float tv) {
        float e   = __builtin_amdgcn_exp2f(-L2E * __builtin_fabsf(xv)); // e^-|x|
        float ope = 1.0f + e;
        float r   = __builtin_amdgcn_rcpf(ope);           // 1/(1+e)
        float sig = (xv >= 0.0f) ? r : e * r;             // stable sigmoid
        float g   = __builtin_fabsf(sig - tv);            // [0,1]
        int bi = (int)(g * 9.9999f);
        bi = bi > (BINS - 1) ? (BINS - 1) : bi;           // ulp safety clamp
        float l2  = __builtin_amdgcn_logf(ope);           // log2(1+e)
        float bce = __builtin_fmaf(-xv, tv, __builtin_fmaxf(xv, 0.0f));
        bce = __builtin_fmaf(LN2, l2, bce);               // + ln(1+e)
        unsigned int q = (unsigned int)__builtin_fmaf(bce, QSCALE, 0.5f);
        atomicAdd(mycol + bi * BLOCK,
                  (1ull << 40) | (unsigned long long)q);  // native ds_add_u64
    };

    for (int tb = blockIdx.x; (long long)tb * TILE < nvec; tb += gridDim.x) {
        const int tile0 = tb * TILE;
        if (tile0 + TILE <= nvec) {
            // -------- full tile: DMA-pipelined path (no barriers) --------
            const int base = tile0 + wid * 64 + lane;     // this lane's r=0 idx
            // prologue: stage rounds 0 and 1 (4 DMAs outstanding)
            GLOAD16(x4 + base,         &stg[0][wid][0]);
            GLOAD16(t4 + base,         &stg[0][wid][1024]);
            GLOAD16(x4 + base + BLOCK, &stg[1][wid][0]);
            GLOAD16(t4 + base + BLOCK, &stg[1][wid][1024]);
#pragma unroll
            for (int r = 0; r < NR - 2; ++r) {
                const int s = r & 1;
                // round r's 2 DMAs landed; r+1's 2 remain in flight
                asm volatile("s_waitcnt vmcnt(2)" ::: "memory");
                float4 X = *(const float4*)&stg[s][wid][lane * 16];
                float4 T = *(const float4*)&stg[s][wid][1024 + lane * 16];
                // WAR guard: slice is in regs before re-staging over it
                asm volatile("s_waitcnt lgkmcnt(0)" ::: "memory");
                GLOAD16(x4 + base + (r + 2) * BLOCK, &stg[s][wid][0]);
                GLOAD16(t4 + base + (r + 2) * BLOCK, &stg[s][wid][1024]);
                proc(X.x, T.x); proc(X.y, T.y); proc(X.z, T.z); proc(X.w, T.w);
            }
            {   // round NR-2 (slot 0): its DMAs + round NR-1's outstanding
                asm volatile("s_waitcnt vmcnt(2)" ::: "memory");
                float4 X = *(const float4*)&stg[0][wid][lane * 16];
                float4 T = *(const float4*)&stg[0][wid][1024 + lane * 16];
                asm volatile("s_waitcnt lgkmcnt(0)" ::: "memory");
                proc(X.x, T.x); proc(X.y, T.y); proc(X.z, T.z); proc(X.w, T.w);
            }
            {   // round NR-1 (slot 1): drain
                asm volatile("s_waitcnt vmcnt(0)" ::: "memory");
                float4 X = *(const float4*)&stg[1][wid][lane * 16];
                float4 T = *(const float4*)&stg[1][wid][1024 + lane * 16];
                asm volatile("s_waitcnt lgkmcnt(0)" ::: "memory");
                proc(X.x, T.x); proc(X.y, T.y); proc(X.z, T.z); proc(X.w, T.w);
            }
        } else {
            // -------- partial tile: plain strided path --------
            for (int i = tile0 + tid; i < nvec; i += BLOCK) {
                float4 X = x4[i]; float4 T = t4[i];
                proc(X.x, T.x); proc(X.y, T.y); proc(X.z, T.z); proc(X.w, T.w);
            }
        }
    }
    // scalar tail (total % 4 != 0; not hit for the bench shape)
    for (int j = nvec * 4 + blockIdx.x * BLOCK + tid; j < total;
         j += gridDim.x * BLOCK)
        proc(xs[j], ts[j]);

    __syncthreads();

    // Block reduce. Field safety (bench shape: 8192 elems/block):
    // count < 2^24 at bit 40; sum <= 8192*7.4e6 ~ 6e10 < 2^40.
    unsigned long long v[BINS];
#pragma unroll
    for (int b = 0; b < BINS; ++b) v[b] = hist[b * BLOCK + tid];
    __syncthreads();                                    // reads done -> reuse

#pragma unroll
    for (int b = 0; b < BINS; ++b) {
        unsigned long long s = v[b];
#pragma unroll
        for (int off = 32; off > 0; off >>= 1)
            s += __shfl_down(s, off);
        if (lane == 0) hist[wid * BINS + b] = s;
    }
    __syncthreads();
    if (tid < BINS) {
        unsigned long long tot = 0ull;
#pragma unroll
        for (int w = 0; w < WAVES; ++w) tot += hist[w * BINS + tid];
        unsigned long long sum_fp = tot & ((1ull << 40) - 1ull);
        unsigned int       cntv   = (unsigned int)(tot >> 40);
        psum[(size_t)blockIdx.x * BINS + tid] =
            (float)((double)sum_fp * 9.5367431640625e-7);   // * 2^-20
        pcnt[(size_t)blockIdx.x * BINS + tid] = cntv;
    }
}

// ---------------------------------------------------------------------------
// Pass 2: strided sweep over partials, wave+LDS reduce, fp32 beta math
// exactly as the reference, final scalar.
// ---------------------------------------------------------------------------

__global__ __launch_bounds__(BLOCK) void ghm_pass2(
        const float* __restrict__ psum, const unsigned int* __restrict__ pcnt,
        float* __restrict__ out, int nblocks, float Nf, double inv_total) {
    double       s[BINS];
    unsigned int c[BINS];
#pragma unroll
    for (int b = 0; b < BINS; ++b) { s[b] = 0.0; c[b] = 0u; }

    for (int i = threadIdx.x; i < nblocks; i += BLOCK) {
#pragma unroll
        for (int b = 0; b < BINS; ++b) {
            s[b] += (double)psum[(size_t)i * BINS + b];
            c[b] += pcnt[(size_t)i * BINS + b];
        }
    }

    __shared__ double       ls[BLOCK / 64][BINS];
    __shared__ unsigned int lc[BLOCK / 64][BINS];
    const int lane = threadIdx.x & 63;
    const int wid  = threadIdx.x >> 6;
#pragma unroll
    for (int b = 0; b < BINS; ++b) {
        double       sb = s[b];
        unsigned int cb = c[b];
#pragma unroll
        for (int off = 32; off > 0; off >>= 1) {
            sb += __shfl_down(sb, off);
            cb += __shfl_down(cb, off);
        }
        if (lane == 0) { ls[wid][b] = sb; lc[wid][b] = cb; }
    }
    __syncthreads();

    if (threadIdx.x == 0) {
        double             bin_sum[BINS];
        unsigned long long bin_cnt[BINS];
#pragma unroll
        for (int b = 0; b < BINS; ++b) {
            double ts = 0.0;
            unsigned long long tc = 0;
#pragma unroll
            for (int w = 0; w < BLOCK / 64; ++w) { ts += ls[w][b]; tc += lc[w][b]; }
            bin_sum[b] = ts;
            bin_cnt[b] = tc;
        }
        float nonempty = 0.0f;
#pragma unroll
        for (int b = 0; b < BINS; ++b) nonempty += (bin_cnt[b] > 0) ? 1.0f : 0.0f;
        double acc = 0.0;
#pragma unroll
        for (int b = 0; b < BINS; ++b) {
            float bc   = (float)bin_cnt[b];            // reference keeps fp32
            float gd   = fmaxf(bc * nonempty, 1e-6f);
            float beta = Nf / gd;
            acc += (double)beta * bin_sum[b];
        }
        out[0] = (float)(acc * inv_total);
    }
}

// ---------------------------------------------------------------------------

extern "C" void kernel_launch(void* const* d_in, const int* in_sizes, int n_in,
                              void* d_out, int out_size, void* d_ws, size_t ws_size,
                              hipStream_t stream) {
    const float* x = (const float*)d_in[0];
    const float* t = (const float*)d_in[1];
    const int total = in_sizes[0];          // 1048576 * 16
    const int nvec  = total / 4;
    const int N     = total / 16;           // x.shape[0] (first dim)

    int nblocks = NBLK;
    size_t per_block = (size_t)BINS * (sizeof(float) + sizeof(unsigned int));
    if ((size_t)nblocks * per_block > ws_size) {
        nblocks = (int)(ws_size / per_block);
        if (nblocks < 1) nblocks = 1;
    }

    float*        psum = (float*)d_ws;
    unsigned int* pcnt = (unsigned int*)((char*)d_ws +
                          (size_t)nblocks * BINS * sizeof(float));

    ghm_pass1<<<nblocks, BLOCK, 0, stream>>>(
        (const float4*)x, (const float4*)t, x, t, psum, pcnt, nvec, total);
    ghm_pass2<<<1, BLOCK, 0, stream>>>(
        psum, pcnt, (float*)d_out, nblocks, (float)N, 1.0 / (double)total);
}

// Round 14
// 42.045 us; speedup vs baseline: 1.0036x; 1.0036x over previous
//
#include <hip/hip_runtime.h>
#include <math.h>

#define BINS 10
#define BLOCK 256
#define WAVES (BLOCK / 64)
#define NR 8                       // pipeline rounds per tile
#define TILE (NR * BLOCK)          // float4s per tile = 2048
#define NBLK 2048

// async global->LDS DMA, 16B per lane, wave-uniform LDS base + lane*16
#define GLOAD16(gsrc, ldst)                                         \
    __builtin_amdgcn_global_load_lds(                               \
        (const __attribute__((address_space(1))) void*)(gsrc),      \
        (__attribute__((address_space(3))) void*)(ldst), 16, 0, 0)

// ---------------------------------------------------------------------------
// Pass 1. R13's proven LDS-DMA double-buffered staging (defeats load-sinking;
// counted vmcnt holds depth) -- but bins now accumulate in REGISTERS:
// 10 predicated fp32 sums + one packed 6bit x 10 u64 counter, flushed per
// tile (<=32 elems/lane/tile, fields can't overflow). ZERO per-element DS
// atomics. (R8-R13 lesson: every structure with 1 ds_add_u64/elem floored
// at ~50us regardless of load pipeline depth -> LDS-atomic RMW is the
// suspected serial resource, ~27us unaccounted DS time at 64cy/wave-op.)
// ---------------------------------------------------------------------------

__global__ __launch_bounds__(BLOCK) void ghm_pass1(
        const float4* __restrict__ x4, const float4* __restrict__ t4,
        const float* __restrict__ xs, const float* __restrict__ ts,
        float* __restrict__ psum, unsigned int* __restrict__ pcnt,
        int nvec, int total) {
    __shared__ __align__(16) unsigned char stg[2][WAVES][2048]; // 16 KiB
    __shared__ float        rs[WAVES][BINS];
    __shared__ unsigned int rc[WAVES][BINS];
    const int tid  = threadIdx.x;
    const int wid  = tid >> 6;
    const int lane = tid & 63;

    const float L2E    = 1.44269504088896f;   // log2(e)
    const float LN2    = 0.69314718055995f;   // ln(2)

    float        sm[BINS];
    unsigned int cnt[BINS];
#pragma unroll
    for (int b = 0; b < BINS; ++b) { sm[b] = 0.0f; cnt[b] = 0u; }
    unsigned long long pc = 0ull;             // packed 6-bit counts

    auto proc = [&](float xv, float tv) {
        float e   = __builtin_amdgcn_exp2f(-L2E * __builtin_fabsf(xv)); // e^-|x|
        float ope = 1.0f + e;
        float r   = __builtin_amdgcn_rcpf(ope);           // 1/(1+e)
        float sig = (xv >= 0.0f) ? r : e * r;             // stable sigmoid
        float g   = __builtin_fabsf(sig - tv);            // [0,1]
        int bi = (int)(g * 9.9999f);
        bi = bi > (BINS - 1) ? (BINS - 1) : bi;           // ulp safety clamp
        float l2  = __builtin_amdgcn_logf(ope);           // log2(1+e)
        float bce = __builtin_fmaf(-xv, tv, __builtin_fmaxf(xv, 0.0f));
        bce = __builtin_fmaf(LN2, l2, bce);               // + ln(1+e)
        pc += 1ull << (6 * bi);
#pragma unroll
        for (int b = 0; b < BINS; ++b)                    // static -> registers
            sm[b] += (bi == b) ? bce : 0.0f;
    };

    for (int tb = blockIdx.x; (long long)tb * TILE < nvec; tb += gridDim.x) {
        const int tile0 = tb * TILE;
        if (tile0 + TILE <= nvec) {
            // -------- full tile: DMA-pipelined path (no block barriers) ----
            const int base = tile0 + wid * 64 + lane;
            GLOAD16(x4 + base,         &stg[0][wid][0]);
            GLOAD16(t4 + base,         &stg[0][wid][1024]);
            GLOAD16(x4 + base + BLOCK, &stg[1][wid][0]);
            GLOAD16(t4 + base + BLOCK, &stg[1][wid][1024]);
#pragma unroll
            for (int r = 0; r < NR - 2; ++r) {
                const int s = r & 1;
                asm volatile("s_waitcnt vmcnt(2)" ::: "memory"); // round r landed
                float4 X = *(const float4*)&stg[s][wid][lane * 16];
                float4 T = *(const float4*)&stg[s][wid][1024 + lane * 16];
                asm volatile("s_waitcnt lgkmcnt(0)" ::: "memory"); // WAR guard
                GLOAD16(x4 + base + (r + 2) * BLOCK, &stg[s][wid][0]);
                GLOAD16(t4 + base + (r + 2) * BLOCK, &stg[s][wid][1024]);
                proc(X.x, T.x); proc(X.y, T.y); proc(X.z, T.z); proc(X.w, T.w);
            }
            {   // round NR-2 (slot 0)
                asm volatile("s_waitcnt vmcnt(2)" ::: "memory");
                float4 X = *(const float4*)&stg[0][wid][lane * 16];
                float4 T = *(const float4*)&stg[0][wid][1024 + lane * 16];
                proc(X.x, T.x); proc(X.y, T.y); proc(X.z, T.z); proc(X.w, T.w);
            }
            {   // round NR-1 (slot 1): drain
                asm volatile("s_waitcnt vmcnt(0)" ::: "memory");
                float4 X = *(const float4*)&stg[1][wid][lane * 16];
                float4 T = *(const float4*)&stg[1][wid][1024 + lane * 16];
                proc(X.x, T.x); proc(X.y, T.y); proc(X.z, T.z); proc(X.w, T.w);
            }
        } else {
            // -------- partial tile: plain strided path --------
            for (int i = tile0 + tid; i < nvec; i += BLOCK) {
                float4 X = x4[i]; float4 T = t4[i];
                proc(X.x, T.x); proc(X.y, T.y); proc(X.z, T.z); proc(X.w, T.w);
            }
        }
        // flush packed counts each tile (32 elems/lane/tile: fields < 33)
#pragma unroll
        for (int b = 0; b < BINS; ++b)
            cnt[b] += (unsigned int)((pc >> (6 * b)) & 63ull);
        pc = 0ull;
    }
    // scalar tail (total % 4 != 0; not hit for the bench shape)
    for (int j = nvec * 4 + blockIdx.x * BLOCK + tid; j < total;
         j += gridDim.x * BLOCK)
        proc(xs[j], ts[j]);
#pragma unroll
    for (int b = 0; b < BINS; ++b)
        cnt[b] += (unsigned int)((pc >> (6 * b)) & 63ull);

    // -------- block reduce: wave shuffle -> LDS -> per-block partial ------
#pragma unroll
    for (int b = 0; b < BINS; ++b) {
        float        s = sm[b];
        unsigned int c = cnt[b];
#pragma unroll
        for (int off = 32; off > 0; off >>= 1) {
            s += __shfl_down(s, off);
            c += __shfl_down(c, off);
        }
        if (lane == 0) { rs[wid][b] = s; rc[wid][b] = c; }
    }
    __syncthreads();
    if (tid < BINS) {
        float        s = 0.0f;
        unsigned int c = 0u;
#pragma unroll
        for (int w = 0; w < WAVES; ++w) { s += rs[w][tid]; c += rc[w][tid]; }
        psum[(size_t)blockIdx.x * BINS + tid] = s;
        pcnt[(size_t)blockIdx.x * BINS + tid] = c;
    }
}

// ---------------------------------------------------------------------------
// Pass 2: strided sweep over partials, wave+LDS reduce, fp32 beta math
// exactly as the reference, final scalar.
// ---------------------------------------------------------------------------

__global__ __launch_bounds__(BLOCK) void ghm_pass2(
        const float* __restrict__ psum, const unsigned int* __restrict__ pcnt,
        float* __restrict__ out, int nblocks, float Nf, double inv_total) {
    double       s[BINS];
    unsigned int c[BINS];
#pragma unroll
    for (int b = 0; b < BINS; ++b) { s[b] = 0.0; c[b] = 0u; }

    for (int i = threadIdx.x; i < nblocks; i += BLOCK) {
#pragma unroll
        for (int b = 0; b < BINS; ++b) {
            s[b] += (double)psum[(size_t)i * BINS + b];
            c[b] += pcnt[(size_t)i * BINS + b];
        }
    }

    __shared__ double       ls[BLOCK / 64][BINS];
    __shared__ unsigned int lc[BLOCK / 64][BINS];
    const int lane = threadIdx.x & 63;
    const int wid  = threadIdx.x >> 6;
#pragma unroll
    for (int b = 0; b < BINS; ++b) {
        double       sb = s[b];
        unsigned int cb = c[b];
#pragma unroll
        for (int off = 32; off > 0; off >>= 1) {
            sb += __shfl_down(sb, off);
            cb += __shfl_down(cb, off);
        }
        if (lane == 0) { ls[wid][b] = sb; lc[wid][b] = cb; }
    }
    __syncthreads();

    if (threadIdx.x == 0) {
        double             bin_sum[BINS];
        unsigned long long bin_cnt[BINS];
#pragma unroll
        for (int b = 0; b < BINS; ++b) {
            double ts = 0.0;
            unsigned long long tc = 0;
#pragma unroll
            for (int w = 0; w < BLOCK / 64; ++w) { ts += ls[w][b]; tc += lc[w][b]; }
            bin_sum[b] = ts;
            bin_cnt[b] = tc;
        }
        float nonempty = 0.0f;
#pragma unroll
        for (int b = 0; b < BINS; ++b) nonempty += (bin_cnt[b] > 0) ? 1.0f : 0.0f;
        double acc = 0.0;
#pragma unroll
        for (int b = 0; b < BINS; ++b) {
            float bc   = (float)bin_cnt[b];            // reference keeps fp32
            float gd   = fmaxf(bc * nonempty, 1e-6f);
            float beta = Nf / gd;
            acc += (double)beta * bin_sum[b];
        }
        out[0] = (float)(acc * inv_total);
    }
}

// ---------------------------------------------------------------------------

extern "C" void kernel_launch(void* const* d_in, const int* in_sizes, int n_in,
                              void* d_out, int out_size, void* d_ws, size_t ws_size,
                              hipStream_t stream) {
    const float* x = (const float*)d_in[0];
    const float* t = (const float*)d_in[1];
    const int total = in_sizes[0];          // 1048576 * 16
    const int nvec  = total / 4;
    const int N     = total / 16;           // x.shape[0] (first dim)

    int nblocks = NBLK;
    size_t per_block = (size_t)BINS * (sizeof(float) + sizeof(unsigned int));
    if ((size_t)nblocks * per_block > ws_size) {
        nblocks = (int)(ws_size / per_block);
        if (nblocks < 1) nblocks = 1;
    }

    float*        psum = (float*)d_ws;
    unsigned int* pcnt = (unsigned int*)((char*)d_ws +
                          (size_t)nblocks * BINS * sizeof(float));

    ghm_pass1<<<nblocks, BLOCK, 0, stream>>>(
        (const float4*)x, (const float4*)t, x, t, psum, pcnt, nvec, total);
    ghm_pass2<<<1, BLOCK, 0, stream>>>(
        psum, pcnt, (float*)d_out, nblocks, (float)N, 1.0 / (double)total);
}